// Round 8
// baseline (997.243 us; speedup 1.0000x reference)
//
#include <hip/hip_runtime.h>
#include <hip/hip_bf16.h>
#include <cmath>

#define TBL (1 << 19)   // T = 2^19 hash table entries per level (power of two)

__device__ __forceinline__ float relu_f(float x) { return fmaxf(x, 0.0f); }

// fp32 -> bf16 bits, round-to-nearest-even
__device__ __forceinline__ unsigned short f2bf(float x) {
    union { float f; unsigned u; } v; v.f = x;
    const unsigned r = v.u + 0x7FFFu + ((v.u >> 16) & 1u);
    return (unsigned short)(r >> 16);
}

typedef __attribute__((ext_vector_type(8))) short short8;   // 8 bf16 = 4 VGPRs (A/B frag)
typedef __attribute__((ext_vector_type(4))) float floatx4;  // C/D frag

// Feature-axis permutation for the register-identity chain (bijective bit
// permutation {k5,k3,k2,k4,k1,k0}): D-tile position (t,q,r) of layer L feeds
// A-element (kc=t>>1, j=((t&1)<<2)|r) of layer L+1 in the SAME lane, iff the
// next weight matrix's K-rows are staged at sperm(k).
__device__ __forceinline__ int sperm(int k) {
    return ((k >> 5) << 5) | (((k >> 2) & 3) << 3) | (((k >> 4) & 1) << 2) | (k & 3);
}

// res_l = floor(16 * 1.3819^l); dense iff (res+1)^3 <= 2^19  (l = 0..4)
#define RES_LIST {16, 22, 30, 42, 58, 80, 111, 153, 212, 294, 406, 561, 775, 1072, 1481, 2047}

// ---------------------------------------------------------------------------
// Symmetric scheduled encode (unchanged — at its request-rate model ceiling:
// ~210M L2 line-requests => ~690us, stable across 3 structural variants).
// ---------------------------------------------------------------------------
__global__ __launch_bounds__(256, 8)
void encode_sched(const float* __restrict__ xyz,
                  const float* __restrict__ table,
                  unsigned* __restrict__ ws_enc,   // u32 = 2 bf16, [level*n + i]
                  int n)
{
    constexpr unsigned RES[16] = RES_LIST;
    constexpr int LEVORD[16] = {5, 0, 6, 1, 7, 2, 8, 3, 9, 4, 10, 11, 12, 13, 14, 15};

    const int xcd      = (int)(blockIdx.x & 7u);
    const unsigned g   = blockIdx.x >> 3;
    const unsigned upb = (unsigned)(n >> 11);     // blocks per (xcd, level) phase
    const int unit     = (int)(g / upb);
    const int slot     = (int)(g % upb);
    const int level    = LEVORD[unit & 15];
    const int i        = xcd * (n >> 3) + slot * 256 + (int)threadIdx.x;
    if (i >= n) return;

    const float px_ = __builtin_nontemporal_load(xyz + 3 * (size_t)i + 0);
    const float py_ = __builtin_nontemporal_load(xyz + 3 * (size_t)i + 1);
    const float pz_ = __builtin_nontemporal_load(xyz + 3 * (size_t)i + 2);

    const unsigned res = RES[level];
    const float fr = (float)res;
    const float posx = px_ * fr, posy = py_ * fr, posz = pz_ * fr;
    const float fx = floorf(posx), fy = floorf(posy), fz = floorf(posz);
    const float wx = posx - fx, wy = posy - fy, wz = posz - fz;
    const unsigned x0 = (unsigned)fx, y0 = (unsigned)fy, z0 = (unsigned)fz;
    const float* tb = table + (size_t)level * (TBL * 2);

    float a0 = 0.0f, a1 = 0.0f;
    const float wx1 = wx, wx0 = 1.0f - wx;

    if (level < 5) {
        const unsigned s = res + 1u;
        const unsigned s2 = s * s;
        const unsigned base = x0 + y0 * s + z0 * s2;
#pragma unroll
        for (int c = 0; c < 4; ++c) {
            const unsigned dy = c & 1, dz = c >> 1;
            const unsigned idx = base + dy * s + dz * s2;
            const float wyz = (dy ? wy : 1.0f - wy) * (dz ? wz : 1.0f - wz);
            const float w0 = wyz * wx0, w1 = wyz * wx1;
            float e0x, e0y, e1x, e1y;
            if (!(idx & 1u)) {
                const float4 f = *reinterpret_cast<const float4*>(tb + 2u * idx);
                e0x = f.x; e0y = f.y; e1x = f.z; e1y = f.w;
            } else {
                const float2 f0 = *reinterpret_cast<const float2*>(tb + 2u * idx);
                const float2 f1 = *reinterpret_cast<const float2*>(tb + 2u * idx + 2u);
                e0x = f0.x; e0y = f0.y; e1x = f1.x; e1y = f1.y;
            }
            a0 = fmaf(e0x, w0, fmaf(e1x, w1, a0));
            a1 = fmaf(e0y, w0, fmaf(e1y, w1, a1));
        }
    } else {
#pragma unroll
        for (int c = 0; c < 4; ++c) {
            const unsigned dy = c & 1, dz = c >> 1;
            const unsigned hh = (y0 + dy) * 2654435761u ^ (z0 + dz) * 805459861u;
            const float wyz = (dy ? wy : 1.0f - wy) * (dz ? wz : 1.0f - wz);
            const float w0 = wyz * wx0, w1 = wyz * wx1;
            const unsigned i0 = (x0 ^ hh) & (unsigned)(TBL - 1);
            if (!(x0 & 1u)) {
                const float4 f = *reinterpret_cast<const float4*>(tb + 2u * (i0 & ~1u));
                const bool hi = (i0 & 1u) != 0u;
                const float e0x = hi ? f.z : f.x, e0y = hi ? f.w : f.y;
                const float e1x = hi ? f.x : f.z, e1y = hi ? f.y : f.w;
                a0 = fmaf(e0x, w0, fmaf(e1x, w1, a0));
                a1 = fmaf(e0y, w0, fmaf(e1y, w1, a1));
            } else {
                const unsigned i1 = ((x0 + 1u) ^ hh) & (unsigned)(TBL - 1);
                const float2 f0 = *reinterpret_cast<const float2*>(tb + 2u * i0);
                const float2 f1 = *reinterpret_cast<const float2*>(tb + 2u * i1);
                a0 = fmaf(f0.x, w0, fmaf(f1.x, w1, a0));
                a1 = fmaf(f0.y, w0, fmaf(f1.y, w1, a1));
            }
        }
    }

    const unsigned pack = (unsigned)f2bf(a0) | ((unsigned)f2bf(a1) << 16);
    __builtin_nontemporal_store(pack, ws_enc + ((size_t)level * n + i));
}

// ---------------------------------------------------------------------------
// MFMA MLP, register-identity chain. Round-7 lesson: the cost is the per-layer
// LDS round-trip (MFMA -> f2bf -> 16x ds_write_b16 -> barrier -> ds_read ->
// MFMA) x5 per tile. This version alternates operand roles so D of one layer
// IS the A-frag of the next in the same lane (weights-as-A for L1/R1 => D
// col=point; activations-as-A for L2/R2), with the hidden-feature axis
// permuted via sperm() baked into ws2/wr2 LDS staging. geo crosses through a
// tiny 640B/wave LDS buffer; R3 (64->3) is a VALU dot + 16-lane shfl reduce
// in fp32. s_act/s_geo/wr3-staging deleted: LDS 40.7 -> 26.6 KB.
// Layouts (HW-verified m89/m91): A: m=lane&15, k=(lane>>4)*8+j;
// B: n=lane&15, k=(lane>>4)*8+j; D: col=lane&15, row=(lane>>4)*4+reg.
// ---------------------------------------------------------------------------
__global__ __launch_bounds__(256)
void mlp_mfma(const unsigned* __restrict__ ws_enc,
              const float* __restrict__ dirv,
              const float* __restrict__ ws1,   // (32,64)
              const float* __restrict__ ws2,   // (64,17)
              const float* __restrict__ wr1,   // (32,64)
              const float* __restrict__ wr2,   // (64,64)
              const float* __restrict__ wr3,   // (64,3)
              float* __restrict__ out,
              int n)
{
    // s_w layout (shorts): ws1 @0 (64*40) | ws2 @2560 (32*72, k sperm'd)
    //                      wr1 @4864 (64*40) | wr2 @7424 (64*72, k sperm'd)
    __shared__ alignas(16) unsigned short s_w[12032];
    __shared__ alignas(8)  unsigned short s_geo[4][16 * 20];  // [point][geo f-1]

    const int tid = threadIdx.x;

    for (int e = tid; e < 12032; e += 256) s_w[e] = 0;
    __syncthreads();
    for (int e = tid; e < 2048; e += 256) { const int k = e >> 6, j = e & 63; s_w[0    + j * 40 + k] = f2bf(ws1[e]); }
    for (int e = tid; e < 1088; e += 256) { const int k = e / 17, j = e % 17; s_w[2560 + j * 72 + sperm(k)] = f2bf(ws2[e]); }
    for (int e = tid; e < 2048; e += 256) { const int k = e >> 6, j = e & 63; s_w[4864 + j * 40 + k] = f2bf(wr1[e]); }
    for (int e = tid; e < 4096; e += 256) { const int k = e >> 6, j = e & 63; s_w[7424 + j * 72 + sperm(k)] = f2bf(wr2[e]); }
    __syncthreads();

    const int wave = tid >> 6;
    const int lane = tid & 63;
    const int q    = lane >> 4;    // quad 0..3
    const int mr   = lane & 15;
    unsigned short* gb = s_geo[wave];
    const int base = blockIdx.x * 1024 + wave * 256;
    if (base >= n) return;

    // per-lane wr3 columns: w3v[t][c] = wr3[f=t*16+mr][c], fp32 (R3 on VALU)
    float w3v[4][3];
#pragma unroll
    for (int t = 0; t < 4; ++t)
#pragma unroll
        for (int c = 0; c < 3; ++c)
            w3v[t][c] = wr3[(t * 16 + mr) * 3 + c];

    const int pt0 = base + mr;
    // prime it=0 prefetch (enc words q*4+t of point mr; dirv of point mr)
    unsigned e0 = ws_enc[(size_t)(q * 4 + 0) * n + pt0];
    unsigned e1 = ws_enc[(size_t)(q * 4 + 1) * n + pt0];
    unsigned e2 = ws_enc[(size_t)(q * 4 + 2) * n + pt0];
    unsigned e3 = ws_enc[(size_t)(q * 4 + 3) * n + pt0];
    float dv0 = dirv[3 * (size_t)pt0 + 0];
    float dv1 = dirv[3 * (size_t)pt0 + 1];
    float dv2 = dirv[3 * (size_t)pt0 + 2];

    union U8 { unsigned u[4]; short8 s; };

#pragma unroll 1
    for (int it = 0; it < 16; ++it) {
        const int pb = base + it * 16;

        unsigned f0 = 0, f1 = 0, f2 = 0, f3 = 0;
        float c0 = 0.f, c1 = 0.f, c2 = 0.f;
        if (it < 15) {
            const int ptn = pt0 + (it + 1) * 16;
            f0 = ws_enc[(size_t)(q * 4 + 0) * n + ptn];
            f1 = ws_enc[(size_t)(q * 4 + 1) * n + ptn];
            f2 = ws_enc[(size_t)(q * 4 + 2) * n + ptn];
            f3 = ws_enc[(size_t)(q * 4 + 3) * n + ptn];
            c0 = dirv[3 * (size_t)ptn + 0];
            c1 = dirv[3 * (size_t)ptn + 1];
            c2 = dirv[3 * (size_t)ptn + 2];
        }

        // ---- B_L1: enc fragment (n=point=mr, k=q*8+j -> word q*4+j/2)
        U8 be; be.u[0] = e0; be.u[1] = e1; be.u[2] = e2; be.u[3] = e3;
        const short8 benc = be.s;

        // ---- L1: A=ws1 (m=h-feature), B=enc. D: col=point, row=h-feat.
        floatx4 h4[4];
#pragma unroll
        for (int t = 0; t < 4; ++t) {
            const short8 a = *reinterpret_cast<const short8*>(s_w + 0 + (t * 16 + mr) * 40 + q * 8);
            floatx4 acc = {0.f, 0.f, 0.f, 0.f};
            h4[t] = __builtin_amdgcn_mfma_f32_16x16x32_bf16(a, benc, acc, 0, 0, 0);
        }

        // ---- A_L2 = relu+bf16 of h4, register identity (sperm'd features)
        short8 A0, A1;
#pragma unroll
        for (int j = 0; j < 4; ++j) {
            A0[j]     = (short)f2bf(fmaxf(h4[0][j], 0.f));
            A0[4 + j] = (short)f2bf(fmaxf(h4[1][j], 0.f));
            A1[j]     = (short)f2bf(fmaxf(h4[2][j], 0.f));
            A1[4 + j] = (short)f2bf(fmaxf(h4[3][j], 0.f));
        }

        // ---- L2: A=h (m=point), B=ws2 (n=geo-feature). D: row=point, col=geo-f.
        floatx4 g0acc = {0.f, 0.f, 0.f, 0.f};
        floatx4 g1acc = {0.f, 0.f, 0.f, 0.f};
        {
            const short8 b00 = *reinterpret_cast<const short8*>(s_w + 2560 + mr * 72 + 0  + q * 8);
            const short8 b01 = *reinterpret_cast<const short8*>(s_w + 2560 + mr * 72 + 32 + q * 8);
            g0acc = __builtin_amdgcn_mfma_f32_16x16x32_bf16(A0, b00, g0acc, 0, 0, 0);
            g0acc = __builtin_amdgcn_mfma_f32_16x16x32_bf16(A1, b01, g0acc, 0, 0, 0);
            const short8 b10 = *reinterpret_cast<const short8*>(s_w + 2560 + (16 + mr) * 72 + 0  + q * 8);
            const short8 b11 = *reinterpret_cast<const short8*>(s_w + 2560 + (16 + mr) * 72 + 32 + q * 8);
            g1acc = __builtin_amdgcn_mfma_f32_16x16x32_bf16(A0, b10, g1acc, 0, 0, 0);
            g1acc = __builtin_amdgcn_mfma_f32_16x16x32_bf16(A1, b11, g1acc, 0, 0, 0);
        }

        // ---- sigma out: geo[p][0] at col mr==0, rows p=q*4+r
        if (mr == 0) {
#pragma unroll
            for (int r = 0; r < 4; ++r)
                out[3 * (size_t)n + (size_t)(pb + q * 4 + r)] = fmaxf(g0acc[r], 0.f);
        }

        // ---- geo -> tiny LDS: geo[p][f] stored at col f-1 (f=1..16), bf16 raw
        if (mr != 0) {
#pragma unroll
            for (int r = 0; r < 4; ++r)
                gb[(q * 4 + r) * 20 + (mr - 1)] = f2bf(g0acc[r]);
        } else {
#pragma unroll
            for (int r = 0; r < 4; ++r)
                gb[(q * 4 + r) * 20 + 15] = f2bf(g1acc[r]);
        }
        __builtin_amdgcn_wave_barrier();

        // ---- SH deg-4 of point mr (all quads compute; used by q<2 lanes)
        const float dx = dv0 * 2.0f - 1.0f;
        const float dy = dv1 * 2.0f - 1.0f;
        const float dz = dv2 * 2.0f - 1.0f;
        const float x2 = dx * dx, y2 = dy * dy, z2 = dz * dz;
        const float xy = dx * dy, yz = dy * dz, xz = dx * dz;
        float sh[16];
        sh[0]  = 0.28209479177387814f;
        sh[1]  = -0.48860251190291987f * dy;
        sh[2]  = 0.48860251190291987f * dz;
        sh[3]  = -0.48860251190291987f * dx;
        sh[4]  = 1.0925484305920792f * xy;
        sh[5]  = -1.0925484305920792f * yz;
        sh[6]  = 0.94617469575756f * z2 - 0.31539156525252f;
        sh[7]  = -1.0925484305920792f * xz;
        sh[8]  = 0.5462742152960396f * (x2 - y2);
        sh[9]  = 0.5900435899266435f * dy * (-3.0f * x2 + y2);
        sh[10] = 2.890611442640554f * xy * dz;
        sh[11] = 0.4570457994644657f * dy * (1.0f - 5.0f * z2);
        sh[12] = 0.3731763325901154f * dz * (5.0f * z2 - 3.0f);
        sh[13] = 0.4570457994644657f * dx * (1.0f - 5.0f * z2);
        sh[14] = 1.445305721320277f * dz * (x2 - y2);
        sh[15] = 0.5900435899266435f * dx * (-x2 + 3.0f * y2);

        // ---- B_R1 (n=point=mr, k=q*8+j): q<2 -> sh[q*8+j]; q>=2 -> geo cols
        const int sb = (q & 1) * 8;
        unsigned shw0 = (unsigned)f2bf(sh[sb + 0]) | ((unsigned)f2bf(sh[sb + 1]) << 16);
        unsigned shw1 = (unsigned)f2bf(sh[sb + 2]) | ((unsigned)f2bf(sh[sb + 3]) << 16);
        unsigned shw2 = (unsigned)f2bf(sh[sb + 4]) | ((unsigned)f2bf(sh[sb + 5]) << 16);
        unsigned shw3 = (unsigned)f2bf(sh[sb + 6]) | ((unsigned)f2bf(sh[sb + 7]) << 16);
        const unsigned* gp = reinterpret_cast<const unsigned*>(gb + mr * 20 + sb);
        U8 br;
        br.u[0] = (q < 2) ? shw0 : gp[0];
        br.u[1] = (q < 2) ? shw1 : gp[1];
        br.u[2] = (q < 2) ? shw2 : gp[2];
        br.u[3] = (q < 2) ? shw3 : gp[3];
        const short8 brgb = br.s;

        // ---- R1: A=wr1 (m=g-feature), B=rgbin. D: col=point, row=g-feat.
        floatx4 gg[4];
#pragma unroll
        for (int t = 0; t < 4; ++t) {
            const short8 a = *reinterpret_cast<const short8*>(s_w + 4864 + (t * 16 + mr) * 40 + q * 8);
            floatx4 acc = {0.f, 0.f, 0.f, 0.f};
            gg[t] = __builtin_amdgcn_mfma_f32_16x16x32_bf16(a, brgb, acc, 0, 0, 0);
        }

        // ---- A_R2 identity
        short8 Ag0, Ag1;
#pragma unroll
        for (int j = 0; j < 4; ++j) {
            Ag0[j]     = (short)f2bf(fmaxf(gg[0][j], 0.f));
            Ag0[4 + j] = (short)f2bf(fmaxf(gg[1][j], 0.f));
            Ag1[j]     = (short)f2bf(fmaxf(gg[2][j], 0.f));
            Ag1[4 + j] = (short)f2bf(fmaxf(gg[3][j], 0.f));
        }

        // ---- R2: A=g (m=point), B=wr2 (n=g2-feature). D: row=point, col=g2-f.
        floatx4 g2[4];
#pragma unroll
        for (int t = 0; t < 4; ++t) {
            const short8 b0 = *reinterpret_cast<const short8*>(s_w + 7424 + (t * 16 + mr) * 72 + 0  + q * 8);
            const short8 b1 = *reinterpret_cast<const short8*>(s_w + 7424 + (t * 16 + mr) * 72 + 32 + q * 8);
            floatx4 acc = {0.f, 0.f, 0.f, 0.f};
            acc = __builtin_amdgcn_mfma_f32_16x16x32_bf16(Ag0, b0, acc, 0, 0, 0);
            acc = __builtin_amdgcn_mfma_f32_16x16x32_bf16(Ag1, b1, acc, 0, 0, 0);
            g2[t] = acc;
        }

        // ---- R3 on VALU: rgb[p][c] = sum_f relu(g2[p][f]) * wr3[f][c]
        // lane (q,mr) holds g2[p=q*4+r][f=t*16+mr]; sum over t in-lane,
        // over mr via 16-lane xor reduce.
        float part[3][4];
#pragma unroll
        for (int c = 0; c < 3; ++c)
#pragma unroll
            for (int r = 0; r < 4; ++r) part[c][r] = 0.f;
#pragma unroll
        for (int t = 0; t < 4; ++t) {
#pragma unroll
            for (int r = 0; r < 4; ++r) {
                const float v = fmaxf(g2[t][r], 0.f);
#pragma unroll
                for (int c = 0; c < 3; ++c) part[c][r] = fmaf(v, w3v[t][c], part[c][r]);
            }
        }
#pragma unroll
        for (int m = 1; m < 16; m <<= 1) {
#pragma unroll
            for (int c = 0; c < 3; ++c)
#pragma unroll
                for (int r = 0; r < 4; ++r)
                    part[c][r] += __shfl_xor(part[c][r], m);
        }
        if (mr == 0) {
#pragma unroll
            for (int r = 0; r < 4; ++r)
                out[3 * (size_t)(pb + q * 4 + r) + 0] = 1.0f / (1.0f + __expf(-part[0][r]));
        } else if (mr == 1) {
#pragma unroll
            for (int r = 0; r < 4; ++r)
                out[3 * (size_t)(pb + q * 4 + r) + 1] = 1.0f / (1.0f + __expf(-part[1][r]));
        } else if (mr == 2) {
#pragma unroll
            for (int r = 0; r < 4; ++r)
                out[3 * (size_t)(pb + q * 4 + r) + 2] = 1.0f / (1.0f + __expf(-part[2][r]));
        }
        __builtin_amdgcn_wave_barrier();

        e0 = f0; e1 = f1; e2 = f2; e3 = f3;
        dv0 = c0; dv1 = c1; dv2 = c2;
    }
}

// ---------------------------------------------------------------------------
// Fallback: fused kernel (used only if ws can't hold enc or n % 2048 != 0).
// ---------------------------------------------------------------------------
__global__ __launch_bounds__(256, 4)
void nerf_fused(const float* __restrict__ xyz,
                const float* __restrict__ dirv,
                const float* __restrict__ table,
                const float* __restrict__ ws1,
                const float* __restrict__ ws2,
                const float* __restrict__ wr1,
                const float* __restrict__ wr2,
                const float* __restrict__ wr3,
                float* __restrict__ out,
                int n)
{
    constexpr unsigned RES[16] = RES_LIST;

    const int i = blockIdx.x * 256 + threadIdx.x;
    if (i >= n) return;

    const float px_ = xyz[3 * (size_t)i + 0];
    const float py_ = xyz[3 * (size_t)i + 1];
    const float pz_ = xyz[3 * (size_t)i + 2];

    float enc[32];
#pragma unroll
    for (int l = 0; l < 16; ++l) {
        const unsigned res = RES[l];
        const float fr = (float)res;
        const float posx = px_ * fr, posy = py_ * fr, posz = pz_ * fr;
        const float fx = floorf(posx), fy = floorf(posy), fz = floorf(posz);
        const float wx = posx - fx, wy = posy - fy, wz = posz - fz;
        const unsigned x0 = (unsigned)fx, y0 = (unsigned)fy, z0 = (unsigned)fz;
        const float* tb = table + (size_t)l * (TBL * 2);
        float a0 = 0.0f, a1 = 0.0f;
#pragma unroll
        for (int c = 0; c < 8; ++c) {
            const unsigned cx = x0 + (c & 1);
            const unsigned cy = y0 + ((c >> 1) & 1);
            const unsigned cz = z0 + ((c >> 2) & 1);
            unsigned idx;
            if (l < 5) {
                const unsigned s = res + 1u;
                idx = cx + cy * s + cz * (s * s);
            } else {
                idx = (cx * 1u) ^ (cy * 2654435761u) ^ (cz * 805459861u);
                idx &= (unsigned)(TBL - 1);
            }
            const float w = ((c & 1) ? wx : 1.0f - wx) *
                            ((c & 2) ? wy : 1.0f - wy) *
                            ((c & 4) ? wz : 1.0f - wz);
            const float2 f = *reinterpret_cast<const float2*>(tb + 2u * idx);
            a0 = fmaf(f.x, w, a0);
            a1 = fmaf(f.y, w, a1);
        }
        enc[2 * l + 0] = a0;
        enc[2 * l + 1] = a1;
    }

    float h[64];
#pragma unroll
    for (int j = 0; j < 64; ++j) h[j] = 0.0f;
#pragma unroll
    for (int k = 0; k < 32; ++k) {
        const float e = enc[k];
#pragma unroll
        for (int j = 0; j < 64; ++j) h[j] = fmaf(e, ws1[k * 64 + j], h[j]);
    }
#pragma unroll
    for (int j = 0; j < 64; ++j) h[j] = relu_f(h[j]);

    float geo[17];
#pragma unroll
    for (int j = 0; j < 17; ++j) geo[j] = 0.0f;
#pragma unroll
    for (int k = 0; k < 64; ++k) {
        const float e = h[k];
#pragma unroll
        for (int j = 0; j < 17; ++j) geo[j] = fmaf(e, ws2[k * 17 + j], geo[j]);
    }
    out[3 * (size_t)n + (size_t)i] = relu_f(geo[0]);

    const float dx = dirv[3 * (size_t)i + 0] * 2.0f - 1.0f;
    const float dy = dirv[3 * (size_t)i + 1] * 2.0f - 1.0f;
    const float dz = dirv[3 * (size_t)i + 2] * 2.0f - 1.0f;
    const float x2 = dx * dx, y2 = dy * dy, z2 = dz * dz;
    const float xy = dx * dy, yz = dy * dz, xz = dx * dz;

    float sh[16];
    sh[0]  = 0.28209479177387814f;
    sh[1]  = -0.48860251190291987f * dy;
    sh[2]  = 0.48860251190291987f * dz;
    sh[3]  = -0.48860251190291987f * dx;
    sh[4]  = 1.0925484305920792f * xy;
    sh[5]  = -1.0925484305920792f * yz;
    sh[6]  = 0.94617469575756f * z2 - 0.31539156525252f;
    sh[7]  = -1.0925484305920792f * xz;
    sh[8]  = 0.5462742152960396f * (x2 - y2);
    sh[9]  = 0.5900435899266435f * dy * (-3.0f * x2 + y2);
    sh[10] = 2.890611442640554f * xy * dz;
    sh[11] = 0.4570457994644657f * dy * (1.0f - 5.0f * z2);
    sh[12] = 0.3731763325901154f * dz * (5.0f * z2 - 3.0f);
    sh[13] = 0.4570457994644657f * dx * (1.0f - 5.0f * z2);
    sh[14] = 1.445305721320277f * dz * (x2 - y2);
    sh[15] = 0.5900435899266435f * dx * (-x2 + 3.0f * y2);

    float g[64];
#pragma unroll
    for (int j = 0; j < 64; ++j) g[j] = 0.0f;
#pragma unroll
    for (int k = 0; k < 16; ++k) {
        const float e = sh[k];
#pragma unroll
        for (int j = 0; j < 64; ++j) g[j] = fmaf(e, wr1[k * 64 + j], g[j]);
    }
#pragma unroll
    for (int k = 16; k < 32; ++k) {
        const float e = geo[k - 15];
#pragma unroll
        for (int j = 0; j < 64; ++j) g[j] = fmaf(e, wr1[k * 64 + j], g[j]);
    }
#pragma unroll
    for (int j = 0; j < 64; ++j) g[j] = relu_f(g[j]);

    float r0 = 0.0f, r1 = 0.0f, r2 = 0.0f;
#pragma unroll
    for (int half = 0; half < 2; ++half) {
        const int j0 = half * 32;
        float g2h[32];
#pragma unroll
        for (int j = 0; j < 32; ++j) g2h[j] = 0.0f;
#pragma unroll
        for (int k = 0; k < 64; ++k) {
            const float e = g[k];
#pragma unroll
            for (int j = 0; j < 32; ++j) g2h[j] = fmaf(e, wr2[k * 64 + j0 + j], g2h[j]);
        }
#pragma unroll
        for (int j = 0; j < 32; ++j) {
            const float e = relu_f(g2h[j]);
            r0 = fmaf(e, wr3[(j0 + j) * 3 + 0], r0);
            r1 = fmaf(e, wr3[(j0 + j) * 3 + 1], r1);
            r2 = fmaf(e, wr3[(j0 + j) * 3 + 2], r2);
        }
    }

    out[3 * (size_t)i + 0] = 1.0f / (1.0f + __expf(-r0));
    out[3 * (size_t)i + 1] = 1.0f / (1.0f + __expf(-r1));
    out[3 * (size_t)i + 2] = 1.0f / (1.0f + __expf(-r2));
}

extern "C" void kernel_launch(void* const* d_in, const int* in_sizes, int n_in,
                              void* d_out, int out_size, void* d_ws, size_t ws_size,
                              hipStream_t stream)
{
    const float* xyz   = (const float*)d_in[0];
    const float* dirv  = (const float*)d_in[1];
    const float* table = (const float*)d_in[2];
    const float* ws1   = (const float*)d_in[3];
    const float* ws2   = (const float*)d_in[4];
    const float* wr1   = (const float*)d_in[5];
    const float* wr2   = (const float*)d_in[6];
    const float* wr3   = (const float*)d_in[7];
    float* out = (float*)d_out;

    const int n = in_sizes[0] / 3;
    dim3 block(256);

    const size_t enc_bytes = (size_t)n * 16 * sizeof(unsigned);   // 134 MB at n=2^21
    if (ws_size >= enc_bytes && n >= 2048 && (n & 2047) == 0) {
        unsigned* ws_enc = (unsigned*)d_ws;
        dim3 grid_enc(8u * 16u * (unsigned)(n >> 11));
        dim3 grid_mlp((unsigned)(n >> 10));   // 1024 points per block
        hipLaunchKernelGGL(encode_sched, grid_enc, block, 0, stream,
                           xyz, table, ws_enc, n);
        hipLaunchKernelGGL(mlp_mfma, grid_mlp, block, 0, stream,
                           ws_enc, dirv, ws1, ws2, wr1, wr2, wr3, out, n);
    } else {
        dim3 grid_mlp((n + 255) / 256);
        hipLaunchKernelGGL(nerf_fused, grid_mlp, block, 0, stream,
                           xyz, dirv, table, ws1, ws2, wr1, wr2, wr3, out, n);
    }
}

// Round 9
// 953.356 us; speedup vs baseline: 1.0460x; 1.0460x over previous
//
#include <hip/hip_runtime.h>
#include <hip/hip_bf16.h>
#include <cmath>

#define TBL (1 << 19)   // T = 2^19 hash table entries per level (power of two)

__device__ __forceinline__ float relu_f(float x) { return fmaxf(x, 0.0f); }

// fp32 -> bf16 bits, round-to-nearest-even
__device__ __forceinline__ unsigned short f2bf(float x) {
    union { float f; unsigned u; } v; v.f = x;
    const unsigned r = v.u + 0x7FFFu + ((v.u >> 16) & 1u);
    return (unsigned short)(r >> 16);
}

typedef __attribute__((ext_vector_type(8))) short short8;   // 8 bf16 = 4 VGPRs (A/B frag)
typedef __attribute__((ext_vector_type(4))) float floatx4;  // C/D frag

// Feature-axis permutation for the register-identity chain (bijective bit
// permutation {k5,k3,k2,k4,k1,k0}): D-tile position (t,q,r) of layer L feeds
// A-element (kc=t>>1, j=((t&1)<<2)|r) of layer L+1 in the SAME lane, iff the
// next weight matrix's K-rows are staged at sperm(k).
__device__ __forceinline__ int sperm(int k) {
    return ((k >> 5) << 5) | (((k >> 2) & 3) << 3) | (((k >> 4) & 1) << 2) | (k & 3);
}

// res_l = floor(16 * 1.3819^l); dense iff (res+1)^3 <= 2^19  (l = 0..4)
#define RES_LIST {16, 22, 30, 42, 58, 80, 111, 153, 212, 294, 406, 561, 775, 1072, 1481, 2047}

// ---------------------------------------------------------------------------
// Symmetric scheduled encode (unchanged — at its request-rate model ceiling:
// ~210M L2 line-requests => ~690us, stable across 3 structural variants).
// ---------------------------------------------------------------------------
__global__ __launch_bounds__(256, 8)
void encode_sched(const float* __restrict__ xyz,
                  const float* __restrict__ table,
                  unsigned* __restrict__ ws_enc,   // u32 = 2 bf16, [level*n + i]
                  int n)
{
    constexpr unsigned RES[16] = RES_LIST;
    constexpr int LEVORD[16] = {5, 0, 6, 1, 7, 2, 8, 3, 9, 4, 10, 11, 12, 13, 14, 15};

    const int xcd      = (int)(blockIdx.x & 7u);
    const unsigned g   = blockIdx.x >> 3;
    const unsigned upb = (unsigned)(n >> 11);     // blocks per (xcd, level) phase
    const int unit     = (int)(g / upb);
    const int slot     = (int)(g % upb);
    const int level    = LEVORD[unit & 15];
    const int i        = xcd * (n >> 3) + slot * 256 + (int)threadIdx.x;
    if (i >= n) return;

    const float px_ = __builtin_nontemporal_load(xyz + 3 * (size_t)i + 0);
    const float py_ = __builtin_nontemporal_load(xyz + 3 * (size_t)i + 1);
    const float pz_ = __builtin_nontemporal_load(xyz + 3 * (size_t)i + 2);

    const unsigned res = RES[level];
    const float fr = (float)res;
    const float posx = px_ * fr, posy = py_ * fr, posz = pz_ * fr;
    const float fx = floorf(posx), fy = floorf(posy), fz = floorf(posz);
    const float wx = posx - fx, wy = posy - fy, wz = posz - fz;
    const unsigned x0 = (unsigned)fx, y0 = (unsigned)fy, z0 = (unsigned)fz;
    const float* tb = table + (size_t)level * (TBL * 2);

    float a0 = 0.0f, a1 = 0.0f;
    const float wx1 = wx, wx0 = 1.0f - wx;

    if (level < 5) {
        const unsigned s = res + 1u;
        const unsigned s2 = s * s;
        const unsigned base = x0 + y0 * s + z0 * s2;
#pragma unroll
        for (int c = 0; c < 4; ++c) {
            const unsigned dy = c & 1, dz = c >> 1;
            const unsigned idx = base + dy * s + dz * s2;
            const float wyz = (dy ? wy : 1.0f - wy) * (dz ? wz : 1.0f - wz);
            const float w0 = wyz * wx0, w1 = wyz * wx1;
            float e0x, e0y, e1x, e1y;
            if (!(idx & 1u)) {
                const float4 f = *reinterpret_cast<const float4*>(tb + 2u * idx);
                e0x = f.x; e0y = f.y; e1x = f.z; e1y = f.w;
            } else {
                const float2 f0 = *reinterpret_cast<const float2*>(tb + 2u * idx);
                const float2 f1 = *reinterpret_cast<const float2*>(tb + 2u * idx + 2u);
                e0x = f0.x; e0y = f0.y; e1x = f1.x; e1y = f1.y;
            }
            a0 = fmaf(e0x, w0, fmaf(e1x, w1, a0));
            a1 = fmaf(e0y, w0, fmaf(e1y, w1, a1));
        }
    } else {
#pragma unroll
        for (int c = 0; c < 4; ++c) {
            const unsigned dy = c & 1, dz = c >> 1;
            const unsigned hh = (y0 + dy) * 2654435761u ^ (z0 + dz) * 805459861u;
            const float wyz = (dy ? wy : 1.0f - wy) * (dz ? wz : 1.0f - wz);
            const float w0 = wyz * wx0, w1 = wyz * wx1;
            const unsigned i0 = (x0 ^ hh) & (unsigned)(TBL - 1);
            if (!(x0 & 1u)) {
                const float4 f = *reinterpret_cast<const float4*>(tb + 2u * (i0 & ~1u));
                const bool hi = (i0 & 1u) != 0u;
                const float e0x = hi ? f.z : f.x, e0y = hi ? f.w : f.y;
                const float e1x = hi ? f.x : f.z, e1y = hi ? f.y : f.w;
                a0 = fmaf(e0x, w0, fmaf(e1x, w1, a0));
                a1 = fmaf(e0y, w0, fmaf(e1y, w1, a1));
            } else {
                const unsigned i1 = ((x0 + 1u) ^ hh) & (unsigned)(TBL - 1);
                const float2 f0 = *reinterpret_cast<const float2*>(tb + 2u * i0);
                const float2 f1 = *reinterpret_cast<const float2*>(tb + 2u * i1);
                a0 = fmaf(f0.x, w0, fmaf(f1.x, w1, a0));
                a1 = fmaf(f0.y, w0, fmaf(f1.y, w1, a1));
            }
        }
    }

    const unsigned pack = (unsigned)f2bf(a0) | ((unsigned)f2bf(a1) << 16);
    __builtin_nontemporal_store(pack, ws_enc + ((size_t)level * n + i));
}

// ---------------------------------------------------------------------------
// MFMA MLP, register-identity chain. Round-8 lesson (rule #20): float sh[16]
// read at runtime index sh[q*8+j] lived in SCRATCH (HBM-backed private mem)
// in EVERY version since round 0 — ~24 scratch accesses/lane/iter explains
// the structure-invariant ~270-300us MLP. Fix: 16 named scalars + cndmask
// selection (all indices compile-time). No other change from round 8.
// ---------------------------------------------------------------------------
__global__ __launch_bounds__(256)
void mlp_mfma(const unsigned* __restrict__ ws_enc,
              const float* __restrict__ dirv,
              const float* __restrict__ ws1,   // (32,64)
              const float* __restrict__ ws2,   // (64,17)
              const float* __restrict__ wr1,   // (32,64)
              const float* __restrict__ wr2,   // (64,64)
              const float* __restrict__ wr3,   // (64,3)
              float* __restrict__ out,
              int n)
{
    // s_w layout (shorts): ws1 @0 (64*40) | ws2 @2560 (32*72, k sperm'd)
    //                      wr1 @4864 (64*40) | wr2 @7424 (64*72, k sperm'd)
    __shared__ alignas(16) unsigned short s_w[12032];
    __shared__ alignas(8)  unsigned short s_geo[4][16 * 20];  // [point][geo f-1]

    const int tid = threadIdx.x;

    for (int e = tid; e < 12032; e += 256) s_w[e] = 0;
    __syncthreads();
    for (int e = tid; e < 2048; e += 256) { const int k = e >> 6, j = e & 63; s_w[0    + j * 40 + k] = f2bf(ws1[e]); }
    for (int e = tid; e < 1088; e += 256) { const int k = e / 17, j = e % 17; s_w[2560 + j * 72 + sperm(k)] = f2bf(ws2[e]); }
    for (int e = tid; e < 2048; e += 256) { const int k = e >> 6, j = e & 63; s_w[4864 + j * 40 + k] = f2bf(wr1[e]); }
    for (int e = tid; e < 4096; e += 256) { const int k = e >> 6, j = e & 63; s_w[7424 + j * 72 + sperm(k)] = f2bf(wr2[e]); }
    __syncthreads();

    const int wave = tid >> 6;
    const int lane = tid & 63;
    const int q    = lane >> 4;    // quad 0..3
    const int mr   = lane & 15;
    unsigned short* gb = s_geo[wave];
    const int base = blockIdx.x * 1024 + wave * 256;
    if (base >= n) return;

    // per-lane wr3 columns: w3v[t][c] = wr3[f=t*16+mr][c], fp32 (R3 on VALU)
    float w3v[4][3];
#pragma unroll
    for (int t = 0; t < 4; ++t)
#pragma unroll
        for (int c = 0; c < 3; ++c)
            w3v[t][c] = wr3[(t * 16 + mr) * 3 + c];

    const int pt0 = base + mr;
    // prime it=0 prefetch (enc words q*4+t of point mr; dirv of point mr)
    unsigned e0 = ws_enc[(size_t)(q * 4 + 0) * n + pt0];
    unsigned e1 = ws_enc[(size_t)(q * 4 + 1) * n + pt0];
    unsigned e2 = ws_enc[(size_t)(q * 4 + 2) * n + pt0];
    unsigned e3 = ws_enc[(size_t)(q * 4 + 3) * n + pt0];
    float dv0 = dirv[3 * (size_t)pt0 + 0];
    float dv1 = dirv[3 * (size_t)pt0 + 1];
    float dv2 = dirv[3 * (size_t)pt0 + 2];

    union U8 { unsigned u[4]; short8 s; };

#pragma unroll 1
    for (int it = 0; it < 16; ++it) {
        const int pb = base + it * 16;

        unsigned f0 = 0, f1 = 0, f2 = 0, f3 = 0;
        float c0 = 0.f, c1 = 0.f, c2 = 0.f;
        if (it < 15) {
            const int ptn = pt0 + (it + 1) * 16;
            f0 = ws_enc[(size_t)(q * 4 + 0) * n + ptn];
            f1 = ws_enc[(size_t)(q * 4 + 1) * n + ptn];
            f2 = ws_enc[(size_t)(q * 4 + 2) * n + ptn];
            f3 = ws_enc[(size_t)(q * 4 + 3) * n + ptn];
            c0 = dirv[3 * (size_t)ptn + 0];
            c1 = dirv[3 * (size_t)ptn + 1];
            c2 = dirv[3 * (size_t)ptn + 2];
        }

        // ---- B_L1: enc fragment (n=point=mr, k=q*8+j -> word q*4+j/2)
        U8 be; be.u[0] = e0; be.u[1] = e1; be.u[2] = e2; be.u[3] = e3;
        const short8 benc = be.s;

        // ---- L1: A=ws1 (m=h-feature), B=enc. D: col=point, row=h-feat.
        floatx4 h4[4];
#pragma unroll
        for (int t = 0; t < 4; ++t) {
            const short8 a = *reinterpret_cast<const short8*>(s_w + 0 + (t * 16 + mr) * 40 + q * 8);
            floatx4 acc = {0.f, 0.f, 0.f, 0.f};
            h4[t] = __builtin_amdgcn_mfma_f32_16x16x32_bf16(a, benc, acc, 0, 0, 0);
        }

        // ---- A_L2 = relu+bf16 of h4, register identity (sperm'd features)
        short8 A0, A1;
#pragma unroll
        for (int j = 0; j < 4; ++j) {
            A0[j]     = (short)f2bf(fmaxf(h4[0][j], 0.f));
            A0[4 + j] = (short)f2bf(fmaxf(h4[1][j], 0.f));
            A1[j]     = (short)f2bf(fmaxf(h4[2][j], 0.f));
            A1[4 + j] = (short)f2bf(fmaxf(h4[3][j], 0.f));
        }

        // ---- L2: A=h (m=point), B=ws2 (n=geo-feature). D: row=point, col=geo-f.
        floatx4 g0acc = {0.f, 0.f, 0.f, 0.f};
        floatx4 g1acc = {0.f, 0.f, 0.f, 0.f};
        {
            const short8 b00 = *reinterpret_cast<const short8*>(s_w + 2560 + mr * 72 + 0  + q * 8);
            const short8 b01 = *reinterpret_cast<const short8*>(s_w + 2560 + mr * 72 + 32 + q * 8);
            g0acc = __builtin_amdgcn_mfma_f32_16x16x32_bf16(A0, b00, g0acc, 0, 0, 0);
            g0acc = __builtin_amdgcn_mfma_f32_16x16x32_bf16(A1, b01, g0acc, 0, 0, 0);
            const short8 b10 = *reinterpret_cast<const short8*>(s_w + 2560 + (16 + mr) * 72 + 0  + q * 8);
            const short8 b11 = *reinterpret_cast<const short8*>(s_w + 2560 + (16 + mr) * 72 + 32 + q * 8);
            g1acc = __builtin_amdgcn_mfma_f32_16x16x32_bf16(A0, b10, g1acc, 0, 0, 0);
            g1acc = __builtin_amdgcn_mfma_f32_16x16x32_bf16(A1, b11, g1acc, 0, 0, 0);
        }

        // ---- sigma out: geo[p][0] at col mr==0, rows p=q*4+r
        if (mr == 0) {
#pragma unroll
            for (int r = 0; r < 4; ++r)
                out[3 * (size_t)n + (size_t)(pb + q * 4 + r)] = fmaxf(g0acc[r], 0.f);
        }

        // ---- geo -> tiny LDS: geo[p][f] stored at col f-1 (f=1..16), bf16 raw
        if (mr != 0) {
#pragma unroll
            for (int r = 0; r < 4; ++r)
                gb[(q * 4 + r) * 20 + (mr - 1)] = f2bf(g0acc[r]);
        } else {
#pragma unroll
            for (int r = 0; r < 4; ++r)
                gb[(q * 4 + r) * 20 + 15] = f2bf(g1acc[r]);
        }
        __builtin_amdgcn_wave_barrier();

        // ---- SH deg-4 of point mr — NAMED SCALARS (no runtime-indexed array,
        // rule #20: arrays with runtime indices are allocated in scratch)
        const float dx = dv0 * 2.0f - 1.0f;
        const float dy = dv1 * 2.0f - 1.0f;
        const float dz = dv2 * 2.0f - 1.0f;
        const float x2 = dx * dx, y2 = dy * dy, z2 = dz * dz;
        const float xy = dx * dy, yz = dy * dz, xz = dx * dz;
        const float s0  = 0.28209479177387814f;
        const float s1  = -0.48860251190291987f * dy;
        const float s2  = 0.48860251190291987f * dz;
        const float s3  = -0.48860251190291987f * dx;
        const float s4  = 1.0925484305920792f * xy;
        const float s5  = -1.0925484305920792f * yz;
        const float s6  = 0.94617469575756f * z2 - 0.31539156525252f;
        const float s7  = -1.0925484305920792f * xz;
        const float s8  = 0.5462742152960396f * (x2 - y2);
        const float s9  = 0.5900435899266435f * dy * (-3.0f * x2 + y2);
        const float s10 = 2.890611442640554f * xy * dz;
        const float s11 = 0.4570457994644657f * dy * (1.0f - 5.0f * z2);
        const float s12 = 0.3731763325901154f * dz * (5.0f * z2 - 3.0f);
        const float s13 = 0.4570457994644657f * dx * (1.0f - 5.0f * z2);
        const float s14 = 1.445305721320277f * dz * (x2 - y2);
        const float s15 = 0.5900435899266435f * dx * (-x2 + 3.0f * y2);

        // lane's 8 SH values: q even -> s0..s7, q odd -> s8..s15 (cndmask)
        const bool qh = (q & 1) != 0;
        const float u0 = qh ? s8  : s0;
        const float u1 = qh ? s9  : s1;
        const float u2 = qh ? s10 : s2;
        const float u3 = qh ? s11 : s3;
        const float u4 = qh ? s12 : s4;
        const float u5 = qh ? s13 : s5;
        const float u6 = qh ? s14 : s6;
        const float u7 = qh ? s15 : s7;
        const unsigned shw0 = (unsigned)f2bf(u0) | ((unsigned)f2bf(u1) << 16);
        const unsigned shw1 = (unsigned)f2bf(u2) | ((unsigned)f2bf(u3) << 16);
        const unsigned shw2 = (unsigned)f2bf(u4) | ((unsigned)f2bf(u5) << 16);
        const unsigned shw3 = (unsigned)f2bf(u6) | ((unsigned)f2bf(u7) << 16);

        // ---- B_R1 (n=point=mr, k=q*8+j): q<2 -> sh; q>=2 -> geo cols (LDS)
        const int sb = (q & 1) * 8;
        const unsigned* gp = reinterpret_cast<const unsigned*>(gb + mr * 20 + sb);
        U8 br;
        br.u[0] = (q < 2) ? shw0 : gp[0];
        br.u[1] = (q < 2) ? shw1 : gp[1];
        br.u[2] = (q < 2) ? shw2 : gp[2];
        br.u[3] = (q < 2) ? shw3 : gp[3];
        const short8 brgb = br.s;

        // ---- R1: A=wr1 (m=g-feature), B=rgbin. D: col=point, row=g-feat.
        floatx4 gg[4];
#pragma unroll
        for (int t = 0; t < 4; ++t) {
            const short8 a = *reinterpret_cast<const short8*>(s_w + 4864 + (t * 16 + mr) * 40 + q * 8);
            floatx4 acc = {0.f, 0.f, 0.f, 0.f};
            gg[t] = __builtin_amdgcn_mfma_f32_16x16x32_bf16(a, brgb, acc, 0, 0, 0);
        }

        // ---- A_R2 identity
        short8 Ag0, Ag1;
#pragma unroll
        for (int j = 0; j < 4; ++j) {
            Ag0[j]     = (short)f2bf(fmaxf(gg[0][j], 0.f));
            Ag0[4 + j] = (short)f2bf(fmaxf(gg[1][j], 0.f));
            Ag1[j]     = (short)f2bf(fmaxf(gg[2][j], 0.f));
            Ag1[4 + j] = (short)f2bf(fmaxf(gg[3][j], 0.f));
        }

        // ---- R2: A=g (m=point), B=wr2 (n=g2-feature). D: row=point, col=g2-f.
        floatx4 g2[4];
#pragma unroll
        for (int t = 0; t < 4; ++t) {
            const short8 b0 = *reinterpret_cast<const short8*>(s_w + 7424 + (t * 16 + mr) * 72 + 0  + q * 8);
            const short8 b1 = *reinterpret_cast<const short8*>(s_w + 7424 + (t * 16 + mr) * 72 + 32 + q * 8);
            floatx4 acc = {0.f, 0.f, 0.f, 0.f};
            acc = __builtin_amdgcn_mfma_f32_16x16x32_bf16(Ag0, b0, acc, 0, 0, 0);
            acc = __builtin_amdgcn_mfma_f32_16x16x32_bf16(Ag1, b1, acc, 0, 0, 0);
            g2[t] = acc;
        }

        // ---- R3 on VALU: rgb[p][c] = sum_f relu(g2[p][f]) * wr3[f][c]
        float part[3][4];
#pragma unroll
        for (int c = 0; c < 3; ++c)
#pragma unroll
            for (int r = 0; r < 4; ++r) part[c][r] = 0.f;
#pragma unroll
        for (int t = 0; t < 4; ++t) {
#pragma unroll
            for (int r = 0; r < 4; ++r) {
                const float v = fmaxf(g2[t][r], 0.f);
#pragma unroll
                for (int c = 0; c < 3; ++c) part[c][r] = fmaf(v, w3v[t][c], part[c][r]);
            }
        }
#pragma unroll
        for (int m = 1; m < 16; m <<= 1) {
#pragma unroll
            for (int c = 0; c < 3; ++c)
#pragma unroll
                for (int r = 0; r < 4; ++r)
                    part[c][r] += __shfl_xor(part[c][r], m);
        }
        if (mr == 0) {
#pragma unroll
            for (int r = 0; r < 4; ++r)
                out[3 * (size_t)(pb + q * 4 + r) + 0] = 1.0f / (1.0f + __expf(-part[0][r]));
        } else if (mr == 1) {
#pragma unroll
            for (int r = 0; r < 4; ++r)
                out[3 * (size_t)(pb + q * 4 + r) + 1] = 1.0f / (1.0f + __expf(-part[1][r]));
        } else if (mr == 2) {
#pragma unroll
            for (int r = 0; r < 4; ++r)
                out[3 * (size_t)(pb + q * 4 + r) + 2] = 1.0f / (1.0f + __expf(-part[2][r]));
        }
        __builtin_amdgcn_wave_barrier();

        e0 = f0; e1 = f1; e2 = f2; e3 = f3;
        dv0 = c0; dv1 = c1; dv2 = c2;
    }
}

// ---------------------------------------------------------------------------
// Fallback: fused kernel (used only if ws can't hold enc or n % 2048 != 0).
// ---------------------------------------------------------------------------
__global__ __launch_bounds__(256, 4)
void nerf_fused(const float* __restrict__ xyz,
                const float* __restrict__ dirv,
                const float* __restrict__ table,
                const float* __restrict__ ws1,
                const float* __restrict__ ws2,
                const float* __restrict__ wr1,
                const float* __restrict__ wr2,
                const float* __restrict__ wr3,
                float* __restrict__ out,
                int n)
{
    constexpr unsigned RES[16] = RES_LIST;

    const int i = blockIdx.x * 256 + threadIdx.x;
    if (i >= n) return;

    const float px_ = xyz[3 * (size_t)i + 0];
    const float py_ = xyz[3 * (size_t)i + 1];
    const float pz_ = xyz[3 * (size_t)i + 2];

    float enc[32];
#pragma unroll
    for (int l = 0; l < 16; ++l) {
        const unsigned res = RES[l];
        const float fr = (float)res;
        const float posx = px_ * fr, posy = py_ * fr, posz = pz_ * fr;
        const float fx = floorf(posx), fy = floorf(posy), fz = floorf(posz);
        const float wx = posx - fx, wy = posy - fy, wz = posz - fz;
        const unsigned x0 = (unsigned)fx, y0 = (unsigned)fy, z0 = (unsigned)fz;
        const float* tb = table + (size_t)l * (TBL * 2);
        float a0 = 0.0f, a1 = 0.0f;
#pragma unroll
        for (int c = 0; c < 8; ++c) {
            const unsigned cx = x0 + (c & 1);
            const unsigned cy = y0 + ((c >> 1) & 1);
            const unsigned cz = z0 + ((c >> 2) & 1);
            unsigned idx;
            if (l < 5) {
                const unsigned s = res + 1u;
                idx = cx + cy * s + cz * (s * s);
            } else {
                idx = (cx * 1u) ^ (cy * 2654435761u) ^ (cz * 805459861u);
                idx &= (unsigned)(TBL - 1);
            }
            const float w = ((c & 1) ? wx : 1.0f - wx) *
                            ((c & 2) ? wy : 1.0f - wy) *
                            ((c & 4) ? wz : 1.0f - wz);
            const float2 f = *reinterpret_cast<const float2*>(tb + 2u * idx);
            a0 = fmaf(f.x, w, a0);
            a1 = fmaf(f.y, w, a1);
        }
        enc[2 * l + 0] = a0;
        enc[2 * l + 1] = a1;
    }

    float h[64];
#pragma unroll
    for (int j = 0; j < 64; ++j) h[j] = 0.0f;
#pragma unroll
    for (int k = 0; k < 32; ++k) {
        const float e = enc[k];
#pragma unroll
        for (int j = 0; j < 64; ++j) h[j] = fmaf(e, ws1[k * 64 + j], h[j]);
    }
#pragma unroll
    for (int j = 0; j < 64; ++j) h[j] = relu_f(h[j]);

    float geo[17];
#pragma unroll
    for (int j = 0; j < 17; ++j) geo[j] = 0.0f;
#pragma unroll
    for (int k = 0; k < 64; ++k) {
        const float e = h[k];
#pragma unroll
        for (int j = 0; j < 17; ++j) geo[j] = fmaf(e, ws2[k * 17 + j], geo[j]);
    }
    out[3 * (size_t)n + (size_t)i] = relu_f(geo[0]);

    const float dx = dirv[3 * (size_t)i + 0] * 2.0f - 1.0f;
    const float dy = dirv[3 * (size_t)i + 1] * 2.0f - 1.0f;
    const float dz = dirv[3 * (size_t)i + 2] * 2.0f - 1.0f;
    const float x2 = dx * dx, y2 = dy * dy, z2 = dz * dz;
    const float xy = dx * dy, yz = dy * dz, xz = dx * dz;

    float sh[16];
    sh[0]  = 0.28209479177387814f;
    sh[1]  = -0.48860251190291987f * dy;
    sh[2]  = 0.48860251190291987f * dz;
    sh[3]  = -0.48860251190291987f * dx;
    sh[4]  = 1.0925484305920792f * xy;
    sh[5]  = -1.0925484305920792f * yz;
    sh[6]  = 0.94617469575756f * z2 - 0.31539156525252f;
    sh[7]  = -1.0925484305920792f * xz;
    sh[8]  = 0.5462742152960396f * (x2 - y2);
    sh[9]  = 0.5900435899266435f * dy * (-3.0f * x2 + y2);
    sh[10] = 2.890611442640554f * xy * dz;
    sh[11] = 0.4570457994644657f * dy * (1.0f - 5.0f * z2);
    sh[12] = 0.3731763325901154f * dz * (5.0f * z2 - 3.0f);
    sh[13] = 0.4570457994644657f * dx * (1.0f - 5.0f * z2);
    sh[14] = 1.445305721320277f * dz * (x2 - y2);
    sh[15] = 0.5900435899266435f * dx * (-x2 + 3.0f * y2);

    float g[64];
#pragma unroll
    for (int j = 0; j < 64; ++j) g[j] = 0.0f;
#pragma unroll
    for (int k = 0; k < 16; ++k) {
        const float e = sh[k];
#pragma unroll
        for (int j = 0; j < 64; ++j) g[j] = fmaf(e, wr1[k * 64 + j], g[j]);
    }
#pragma unroll
    for (int k = 16; k < 32; ++k) {
        const float e = geo[k - 15];
#pragma unroll
        for (int j = 0; j < 64; ++j) g[j] = fmaf(e, wr1[k * 64 + j], g[j]);
    }
#pragma unroll
    for (int j = 0; j < 64; ++j) g[j] = relu_f(g[j]);

    float r0 = 0.0f, r1 = 0.0f, r2 = 0.0f;
#pragma unroll
    for (int half = 0; half < 2; ++half) {
        const int j0 = half * 32;
        float g2h[32];
#pragma unroll
        for (int j = 0; j < 32; ++j) g2h[j] = 0.0f;
#pragma unroll
        for (int k = 0; k < 64; ++k) {
            const float e = g[k];
#pragma unroll
            for (int j = 0; j < 32; ++j) g2h[j] = fmaf(e, wr2[k * 64 + j0 + j], g2h[j]);
        }
#pragma unroll
        for (int j = 0; j < 32; ++j) {
            const float e = relu_f(g2h[j]);
            r0 = fmaf(e, wr3[(j0 + j) * 3 + 0], r0);
            r1 = fmaf(e, wr3[(j0 + j) * 3 + 1], r1);
            r2 = fmaf(e, wr3[(j0 + j) * 3 + 2], r2);
        }
    }

    out[3 * (size_t)i + 0] = 1.0f / (1.0f + __expf(-r0));
    out[3 * (size_t)i + 1] = 1.0f / (1.0f + __expf(-r1));
    out[3 * (size_t)i + 2] = 1.0f / (1.0f + __expf(-r2));
}

extern "C" void kernel_launch(void* const* d_in, const int* in_sizes, int n_in,
                              void* d_out, int out_size, void* d_ws, size_t ws_size,
                              hipStream_t stream)
{
    const float* xyz   = (const float*)d_in[0];
    const float* dirv  = (const float*)d_in[1];
    const float* table = (const float*)d_in[2];
    const float* ws1   = (const float*)d_in[3];
    const float* ws2   = (const float*)d_in[4];
    const float* wr1   = (const float*)d_in[5];
    const float* wr2   = (const float*)d_in[6];
    const float* wr3   = (const float*)d_in[7];
    float* out = (float*)d_out;

    const int n = in_sizes[0] / 3;
    dim3 block(256);

    const size_t enc_bytes = (size_t)n * 16 * sizeof(unsigned);   // 134 MB at n=2^21
    if (ws_size >= enc_bytes && n >= 2048 && (n & 2047) == 0) {
        unsigned* ws_enc = (unsigned*)d_ws;
        dim3 grid_enc(8u * 16u * (unsigned)(n >> 11));
        dim3 grid_mlp((unsigned)(n >> 10));   // 1024 points per block
        hipLaunchKernelGGL(encode_sched, grid_enc, block, 0, stream,
                           xyz, table, ws_enc, n);
        hipLaunchKernelGGL(mlp_mfma, grid_mlp, block, 0, stream,
                           ws_enc, dirv, ws1, ws2, wr1, wr2, wr3, out, n);
    } else {
        dim3 grid_mlp((n + 255) / 256);
        hipLaunchKernelGGL(nerf_fused, grid_mlp, block, 0, stream,
                           xyz, dirv, table, ws1, ws2, wr1, wr2, wr3, out, n);
    }
}